// Round 1
// baseline (705.356 us; speedup 1.0000x reference)
//
#include <hip/hip_runtime.h>

typedef _Float16 f16;
typedef _Float16 f16x8 __attribute__((ext_vector_type(8)));
typedef _Float16 f16x4 __attribute__((ext_vector_type(4)));
typedef float    f32x4 __attribute__((ext_vector_type(4)));

#define H  128
#define G3 384
#define AH 36

__device__ __forceinline__ float sigmoidf_(float x){ return 1.f/(1.f+__expf(-x)); }
// tanh via sigmoid form: no inf/inf NaN at extremes
__device__ __forceinline__ float tanhf_(float x){ return 2.f/(1.f+__expf(-2.f*x)) - 1.f; }

// swizzled LDS tile accessor for a [16][128] f16 tile (row stride 256B).
// XOR bits 4-6 of the byte offset with row&7: breaks the 16-way bank conflict
// of 16B frag reads at 256B row stride down to 2-way (free).
__device__ __forceinline__ f16* tptr(f16* base, int row, int kbyte){
  return (f16*)((char*)base + row*256 + (kbyte ^ ((row & 7) << 4)));
}
__device__ __forceinline__ const f16* tptrc(const f16* base, int row, int kbyte){
  return (const f16*)((const char*)base + row*256 + (kbyte ^ ((row & 7) << 4)));
}

// ---------------- prep: weights fp32 -> fp16, lengths ----------------
__global__ void prep_weights(const float* __restrict__ a, const float* __restrict__ b,
                             const float* __restrict__ c, const float* __restrict__ d,
                             f16* __restrict__ dst)
{
  int i = blockIdx.x * 256 + threadIdx.x;
  if (i >= 4 * G3 * H) return;
  int m = i / (G3 * H), j = i % (G3 * H);
  const float* s = (m == 0) ? a : (m == 1) ? b : (m == 2) ? c : d;
  dst[i] = (f16)s[j];
}

__global__ void prep_len(const int* __restrict__ mask, int* __restrict__ len, int T, int B)
{
  int b = blockIdx.x * 256 + threadIdx.x;
  if (b >= B) return;
  int s = 0;
  for (int t = 0; t < T; ++t) s += (mask[(size_t)b * T + t] > 0);
  len[b] = s;
}

// ---------------- fused GRU / AUGRU scan ----------------
// One block = 16 batch rows, 8 waves. Wave w owns hidden cols [16w,16w+16).
// Weights held in VGPRs as MFMA B-fragments. Per step:
//   acc_X = x_t @ Wih^T, acc_H = h @ Whh^T  (16x16x32 f16 MFMA, fp32 acc)
//   gates in fp32 on the C-fragment layout; h_old kept in registers.
template<bool AUG>
__global__ __launch_bounds__(512)
void scan_kernel(const float* __restrict__ xf32,  // GRU input  [B,T,H] f32
                 const f16*   __restrict__ xf16,  // AUGRU input (hist) [B,T,H] f16
                 const f16*   __restrict__ Wih,   // [3H][H] f16
                 const f16*   __restrict__ Whh,   // [3H][H] f16
                 const float* __restrict__ bih,
                 const float* __restrict__ bhh,
                 const float* __restrict__ att,   // [B,T] (AUG)
                 const int*   __restrict__ len,   // [B]   (AUG)
                 f16*         __restrict__ histo, // [B,T,H] f16 (GRU)
                 float*       __restrict__ outp,  // [B,H]       (AUG)
                 int T)
{
  __shared__ f16  xs[2][16 * H];
  __shared__ f16  hs[2][16 * H];
  __shared__ float atts[2][16];

  const int tid = threadIdx.x;
  const int w   = tid >> 6;
  const int l   = tid & 63;
  const int l16 = l & 15;
  const int lhi = l >> 4;
  const int b0  = blockIdx.x * 16;
  const int c   = w * 16 + l16;          // hidden column this lane owns in gates

  // B-fragments of the weights, resident in VGPRs (24 x f16x8 = 96 VGPR)
  f16x8 wih[3][4], whh[3][4];
  #pragma unroll
  for (int g = 0; g < 3; ++g)
    #pragma unroll
    for (int q = 0; q < 4; ++q) {
      int off = (g * H + w * 16 + l16) * H + q * 32 + lhi * 8;
      wih[g][q] = *(const f16x8*)(Wih + off);
      whh[g][q] = *(const f16x8*)(Whh + off);
    }

  const float bs_r = bih[c]       + bhh[c];
  const float bs_z = bih[H + c]   + bhh[H + c];
  const float bx_n = bih[2*H + c];
  const float bh_n = bhh[2*H + c];

  int   rr[4], lens[4];
  float hold[4];
  #pragma unroll
  for (int i = 0; i < 4; ++i) {
    rr[i]   = lhi * 4 + i;               // C-fragment row = batch row (fixed per lane)
    hold[i] = 0.f;
    lens[i] = 0;
    if (AUG) lens[i] = len[b0 + rr[i]];
  }

  // prologue: zero h buf 0, stage x_0 (+att_0)
  {
    const int srow = tid >> 5, cc = tid & 31;
    f16x4 z = {(f16)0, (f16)0, (f16)0, (f16)0};
    *(f16x4*)tptr(hs[0], srow, cc * 8) = z;
    if (AUG) {
      f16x4 v = *(const f16x4*)(xf16 + ((size_t)(b0 + srow) * T) * H + cc * 4);
      *(f16x4*)tptr(xs[0], srow, cc * 8) = v;
      if (tid < 16) atts[0][tid] = att[(size_t)(b0 + tid) * T];
    } else {
      f32x4 v = *(const f32x4*)(xf32 + ((size_t)(b0 + srow) * T) * H + cc * 4);
      f16x4 h4 = {(f16)v.x, (f16)v.y, (f16)v.z, (f16)v.w};
      *(f16x4*)tptr(xs[0], srow, cc * 8) = h4;
    }
  }
  __syncthreads();

  for (int t = 0; t < T; ++t) {
    const int cur = t & 1, nxt = cur ^ 1;
    const int srow = tid >> 5, cc = tid & 31;

    // prefetch next timestep's input (consumed after the gates -> latency hidden)
    const bool hn_ = (t + 1 < T);
    f32x4 p32 = {0.f, 0.f, 0.f, 0.f};
    f16x4 p16 = {(f16)0, (f16)0, (f16)0, (f16)0};
    float pat = 0.f;
    if (hn_) {
      if (AUG) {
        p16 = *(const f16x4*)(xf16 + ((size_t)(b0 + srow) * T + (t + 1)) * H + cc * 4);
        if (tid < 16) pat = att[(size_t)(b0 + tid) * T + (t + 1)];
      } else {
        p32 = *(const f32x4*)(xf32 + ((size_t)(b0 + srow) * T + (t + 1)) * H + cc * 4);
      }
    }

    // A-fragments of x_t and h_t
    f16x8 xa[4], ha[4];
    #pragma unroll
    for (int q = 0; q < 4; ++q) {
      xa[q] = *(const f16x8*)tptrc(xs[cur], l16, q * 64 + lhi * 16);
      ha[q] = *(const f16x8*)tptrc(hs[cur], l16, q * 64 + lhi * 16);
    }

    f32x4 aXr = {0,0,0,0}, aXz = {0,0,0,0}, aXn = {0,0,0,0};
    f32x4 aHr = {0,0,0,0}, aHz = {0,0,0,0}, aHn = {0,0,0,0};
    #pragma unroll
    for (int q = 0; q < 4; ++q) {
      aXr = __builtin_amdgcn_mfma_f32_16x16x32_f16(xa[q], wih[0][q], aXr, 0, 0, 0);
      aXz = __builtin_amdgcn_mfma_f32_16x16x32_f16(xa[q], wih[1][q], aXz, 0, 0, 0);
      aXn = __builtin_amdgcn_mfma_f32_16x16x32_f16(xa[q], wih[2][q], aXn, 0, 0, 0);
      aHr = __builtin_amdgcn_mfma_f32_16x16x32_f16(ha[q], whh[0][q], aHr, 0, 0, 0);
      aHz = __builtin_amdgcn_mfma_f32_16x16x32_f16(ha[q], whh[1][q], aHz, 0, 0, 0);
      aHn = __builtin_amdgcn_mfma_f32_16x16x32_f16(ha[q], whh[2][q], aHn, 0, 0, 0);
    }

    float atv[4];
    if (AUG) {
      #pragma unroll
      for (int i = 0; i < 4; ++i) atv[i] = atts[cur][rr[i]];
    }

    #pragma unroll
    for (int i = 0; i < 4; ++i) {
      float rg = sigmoidf_(aXr[i] + aHr[i] + bs_r);
      float gz = sigmoidf_(aXz[i] + aHz[i] + bs_z);
      float ng = tanhf_(aXn[i] + bx_n + rg * (aHn[i] + bh_n));
      float hnew;
      if (AUG) {
        float u = gz * atv[i];
        hnew = (1.f - u) * hold[i] + u * ng;
      } else {
        hnew = (1.f - gz) * ng + gz * hold[i];
      }
      hold[i] = hnew;
      *tptr(hs[nxt], rr[i], 2 * c) = (f16)hnew;   // h for next step's A-frag
      if (!AUG) {
        histo[((size_t)(b0 + rr[i]) * T + t) * H + c] = (f16)hnew;
      } else {
        if (t == lens[i] - 1) outp[(size_t)(b0 + rr[i]) * H + c] = hnew;
      }
    }

    // write staged next-step input (prefetch has had MFMA+gates to land)
    if (hn_) {
      if (AUG) {
        *(f16x4*)tptr(xs[nxt], srow, cc * 8) = p16;
        if (tid < 16) atts[nxt][tid] = pat;
      } else {
        f16x4 h4 = {(f16)p32.x, (f16)p32.y, (f16)p32.z, (f16)p32.w};
        *(f16x4*)tptr(xs[nxt], srow, cc * 8) = h4;
      }
    }
    __syncthreads();
  }
}

// ---------------- DIN attention: per-b effective weight + masked softmax ----------------
// feat·W1_u = [q·(W1a+W1c)_u + b1_u] + h·[(W1b - W1c) + q⊙W1d]_u
__global__ __launch_bounds__(256)
void attn_kernel(const float* __restrict__ query,
                 const f16*   __restrict__ hist,
                 const int*   __restrict__ mask,
                 const float* __restrict__ W1,   // [36][4H]
                 const float* __restrict__ b1,
                 const float* __restrict__ W2,   // [1][36]
                 const float* __restrict__ b2,
                 float*       __restrict__ attv, // [B,T]
                 int T)
{
  __shared__ float qs[H];
  __shared__ float Wq[AH][H];
  __shared__ float qc[AH];
  __shared__ float red[256];

  const int tid = threadIdx.x;
  const int b   = blockIdx.x;

  if (tid < H) qs[tid] = query[b * H + tid];
  __syncthreads();

  for (int i = tid; i < AH * H; i += 256) {
    int u = i >> 7, k = i & (H - 1);
    const float* r = W1 + u * 4 * H;
    Wq[u][k] = r[H + k] - r[2 * H + k] + qs[k] * r[3 * H + k];
  }
  if (tid < AH) {
    const float* r = W1 + tid * 4 * H;
    float s = b1[tid];
    for (int k = 0; k < H; ++k) s += qs[k] * (r[k] + r[2 * H + k]);
    qc[tid] = s;
  }
  __syncthreads();

  float logit = -1e30f;
  int   mk = 0;
  const int t = tid;
  if (t < T) {
    mk = mask[(size_t)b * T + t];
    float acc[AH];
    #pragma unroll
    for (int u = 0; u < AH; ++u) acc[u] = qc[u];
    const f16* hr = hist + ((size_t)b * T + t) * H;
    for (int kc = 0; kc < H / 8; ++kc) {
      f16x8 hv = *(const f16x8*)(hr + kc * 8);
      float hf[8];
      #pragma unroll
      for (int j = 0; j < 8; ++j) hf[j] = (float)hv[j];
      #pragma unroll
      for (int u = 0; u < AH; ++u) {
        f32x4 w0 = *(const f32x4*)&Wq[u][kc * 8];
        f32x4 w1 = *(const f32x4*)&Wq[u][kc * 8 + 4];
        acc[u] += hf[0]*w0.x + hf[1]*w0.y + hf[2]*w0.z + hf[3]*w0.w
                + hf[4]*w1.x + hf[5]*w1.y + hf[6]*w1.z + hf[7]*w1.w;
      }
    }
    float lg = b2[0];
    #pragma unroll
    for (int u = 0; u < AH; ++u) lg += sigmoidf_(acc[u]) * W2[u];
    logit = (mk > 0) ? lg : -1e30f;
  }

  // masked softmax over T within the block
  red[tid] = logit; __syncthreads();
  for (int s = 128; s > 0; s >>= 1) { if (tid < s) red[tid] = fmaxf(red[tid], red[tid + s]); __syncthreads(); }
  float mx = red[0]; __syncthreads();
  float ev = (t < T && mk > 0) ? __expf(logit - mx) : 0.f;
  red[tid] = ev; __syncthreads();
  for (int s = 128; s > 0; s >>= 1) { if (tid < s) red[tid] += red[tid + s]; __syncthreads(); }
  float sm = red[0];
  if (t < T) attv[(size_t)b * T + t] = ev / sm;
}

// ---------------- host ----------------
extern "C" void kernel_launch(void* const* d_in, const int* in_sizes, int n_in,
                              void* d_out, int out_size, void* d_ws, size_t ws_size,
                              hipStream_t stream)
{
  const float* query = (const float*)d_in[0];
  const float* ub    = (const float*)d_in[1];
  const int*   mask  = (const int*)d_in[2];
  const float* gWih  = (const float*)d_in[3];
  const float* gWhh  = (const float*)d_in[4];
  const float* gbih  = (const float*)d_in[5];
  const float* gbhh  = (const float*)d_in[6];
  const float* aW1   = (const float*)d_in[7];
  const float* ab1   = (const float*)d_in[8];
  const float* aW2   = (const float*)d_in[9];
  const float* ab2   = (const float*)d_in[10];
  const float* uWih  = (const float*)d_in[11];
  const float* uWhh  = (const float*)d_in[12];
  const float* ubih  = (const float*)d_in[13];
  const float* ubhh  = (const float*)d_in[14];

  const int B = in_sizes[0] / H;            // 1024
  const int T = in_sizes[1] / in_sizes[0];  // 200

  // workspace layout
  char*  ws   = (char*)d_ws;
  f16*   wf   = (f16*)ws;                                   // 4 * 384*128 f16 = 393216 B
  int*   len  = (int*)(ws + 393216);                        // B * 4
  float* attb = (float*)(ws + 393216 + 4096);               // B*T*4
  f16*   hist = (f16*)(ws + 393216 + 4096 + (size_t)B * T * 4); // B*T*H f16

  prep_weights<<<(4 * G3 * H + 255) / 256, 256, 0, stream>>>(gWih, gWhh, uWih, uWhh, wf);
  prep_len<<<(B + 255) / 256, 256, 0, stream>>>(mask, len, T, B);

  scan_kernel<false><<<B / 16, 512, 0, stream>>>(
      ub, (const f16*)nullptr, wf, wf + G3 * H, gbih, gbhh,
      (const float*)nullptr, (const int*)nullptr, hist, (float*)nullptr, T);

  attn_kernel<<<B, 256, 0, stream>>>(query, hist, mask, aW1, ab1, aW2, ab2, attb, T);

  scan_kernel<true><<<B / 16, 512, 0, stream>>>(
      (const float*)nullptr, hist, wf + 2 * G3 * H, wf + 3 * G3 * H, ubih, ubhh,
      attb, len, (f16*)nullptr, (float*)d_out, T);
}

// Round 3
// 618.555 us; speedup vs baseline: 1.1403x; 1.1403x over previous
//
#include <hip/hip_runtime.h>

typedef _Float16 f16;
typedef _Float16 f16x8 __attribute__((ext_vector_type(8)));
typedef _Float16 f16x4 __attribute__((ext_vector_type(4)));
typedef float    f32x4 __attribute__((ext_vector_type(4)));

#define H  128
#define G3 384
#define AH 36

__device__ __forceinline__ float sigmoidf_(float x){ return 1.f/(1.f+__expf(-x)); }
// tanh via sigmoid form: no inf/inf NaN at extremes
__device__ __forceinline__ float tanhf_(float x){ return 2.f/(1.f+__expf(-2.f*x)) - 1.f; }

// swizzled LDS tile accessor for a [16][128] f16 tile (row stride 256B).
// XOR bits 4-6 of the byte offset with row&7 (pattern proven correct in R1).
__device__ __forceinline__ f16* tptr(f16* base, int row, int kbyte){
  return (f16*)((char*)base + row*256 + (kbyte ^ ((row & 7) << 4)));
}
__device__ __forceinline__ const f16* tptrc(const f16* base, int row, int kbyte){
  return (const f16*)((const char*)base + row*256 + (kbyte ^ ((row & 7) << 4)));
}

// ---------------- prep: weights fp32 -> fp16, lengths ----------------
__global__ void prep_weights(const float* __restrict__ a, const float* __restrict__ b,
                             const float* __restrict__ c, const float* __restrict__ d,
                             f16* __restrict__ dst)
{
  int i = blockIdx.x * 256 + threadIdx.x;
  if (i >= 4 * G3 * H) return;
  int m = i / (G3 * H), j = i % (G3 * H);
  const float* s = (m == 0) ? a : (m == 1) ? b : (m == 2) ? c : d;
  dst[i] = (f16)s[j];
}

__global__ void prep_len(const int* __restrict__ mask, int* __restrict__ len, int T, int B)
{
  int b = blockIdx.x * 256 + threadIdx.x;
  if (b >= B) return;
  int s = 0;
  for (int t = 0; t < T; ++t) s += (mask[(size_t)b * T + t] > 0);
  len[b] = s;
}

// ---------------- fused GRU / AUGRU scan (v2, macro-shadowing fixed) ----------------
// One block = 16 batch rows, 8 waves. Wave w owns gate/hidden cols [16w,16w+16).
// OPERAND-SWAPPED MFMA: D = W_chunk · input^T, so the C-fragment per lane is
// (batch row = l16) x (4 consecutive cols = c4..c4+3). Bias enters as the MFMA
// C initializer. Weights resident in VGPRs (launch_bounds(512,2) -> 256 VGPR cap).
template<bool AUG>
__global__ __launch_bounds__(512, 2)
void scan_kernel(const float* __restrict__ xf32,  // GRU input  [B,T,H] f32
                 const f16*   __restrict__ xf16,  // AUGRU input (hist) [B,T,H] f16
                 const f16*   __restrict__ Wih,   // [3H][H] f16
                 const f16*   __restrict__ Whh,   // [3H][H] f16
                 const float* __restrict__ bih,
                 const float* __restrict__ bhh,
                 const float* __restrict__ att,   // [B,T] (AUG)
                 const int*   __restrict__ len,   // [B]   (AUG)
                 f16*         __restrict__ histo, // [B,T,H] f16 (GRU)
                 float*       __restrict__ outp,  // [B,H]       (AUG)
                 int T)
{
  __shared__ f16  xs[2][16 * H];
  __shared__ f16  hs[2][16 * H];
  __shared__ float atts[2][16];

  const int tid = threadIdx.x;
  const int w   = tid >> 6;
  const int l   = tid & 63;
  const int l16 = l & 15;
  const int lhi = l >> 4;
  const int b0  = blockIdx.x * 16;
  const int colb = w * 16;
  const int c4   = colb + lhi * 4;       // 4 consecutive gate cols this lane owns
  const int srow = tid >> 5, cc = tid & 31;

  // Weight fragments, resident in VGPRs (24 x f16x8 = 96 VGPR).
  f16x8 wih[3][4], whh[3][4];
  #pragma unroll
  for (int g = 0; g < 3; ++g)
    #pragma unroll
    for (int q = 0; q < 4; ++q) {
      int off = (g * H + colb + l16) * H + q * 32 + lhi * 8;
      wih[g][q] = *(const f16x8*)(Wih + off);
      whh[g][q] = *(const f16x8*)(Whh + off);
    }

  // bias vectors for the lane's 4 cols (enter MFMA as C-init)
  f32x4 bR  = *(const f32x4*)(bih + c4);
  { f32x4 t2 = *(const f32x4*)(bhh + c4);      bR  += t2; }
  f32x4 bZ  = *(const f32x4*)(bih + H + c4);
  { f32x4 t2 = *(const f32x4*)(bhh + H + c4);  bZ  += t2; }
  f32x4 bXn = *(const f32x4*)(bih + 2*H + c4);
  f32x4 bHn = *(const f32x4*)(bhh + 2*H + c4);

  float hold[4] = {0.f, 0.f, 0.f, 0.f};
  int len_l = 0;
  if (AUG) len_l = len[b0 + l16];

  // prologue: zero h buf 0, stage x_0 (+att_0), prefetch x_1 (+att_1)
  {
    f16x4 z4 = {(f16)0, (f16)0, (f16)0, (f16)0};
    *(f16x4*)tptr(hs[0], srow, cc * 8) = z4;
    if (AUG) {
      f16x4 v = *(const f16x4*)(xf16 + ((size_t)(b0 + srow) * T) * H + cc * 4);
      *(f16x4*)tptr(xs[0], srow, cc * 8) = v;
      if (tid < 16) atts[0][tid] = att[(size_t)(b0 + tid) * T];
    } else {
      f32x4 v = *(const f32x4*)(xf32 + ((size_t)(b0 + srow) * T) * H + cc * 4);
      f16x4 h4 = {(f16)v.x, (f16)v.y, (f16)v.z, (f16)v.w};
      *(f16x4*)tptr(xs[0], srow, cc * 8) = h4;
    }
  }
  f32x4 Pa32 = {0,0,0,0}, Pb32 = {0,0,0,0};
  f16x4 Pa16 = {(f16)0,(f16)0,(f16)0,(f16)0}, Pb16 = Pa16;
  float Aa = 0.f, Ab = 0.f;
  if (AUG) {
    Pa16 = *(const f16x4*)(xf16 + ((size_t)(b0 + srow) * T + 1) * H + cc * 4);
    if (tid < 16) Aa = att[(size_t)(b0 + tid) * T + 1];
  } else {
    Pa32 = *(const f32x4*)(xf32 + ((size_t)(b0 + srow) * T + 1) * H + cc * 4);
  }
  __syncthreads();

// NOTE: all macro-internal names are suffixed (t5_/cur_/nxt_) so that the
// macro ARGUMENT expression (e.g. "t + 1") can never capture an inner name.
#define STEP(targ_, PW32, PL32, PW16, PL16, AW, AL)                            \
  {                                                                            \
    const int t5_  = (targ_);                                                  \
    const int cur_ = t5_ & 1, nxt_ = cur_ ^ 1;                                 \
    /* issue depth-2 prefetch: x_{t+2} (+att_{t+2}) */                         \
    if (t5_ + 2 < T) {                                                         \
      if (AUG) {                                                               \
        PL16 = *(const f16x4*)(xf16 + ((size_t)(b0+srow)*T + t5_ + 2)*H + cc*4); \
        if (tid < 16) AL = att[(size_t)(b0+tid)*T + t5_ + 2];                  \
      } else {                                                                 \
        PL32 = *(const f32x4*)(xf32 + ((size_t)(b0+srow)*T + t5_ + 2)*H + cc*4); \
      }                                                                        \
    }                                                                          \
    /* input B-fragments (col = batch row = l16) */                            \
    f16x8 xb[4], hb[4];                                                        \
    _Pragma("unroll")                                                          \
    for (int q = 0; q < 4; ++q) {                                              \
      xb[q] = *(const f16x8*)tptrc((const f16*)xs[cur_], l16, q*64 + lhi*16);  \
      hb[q] = *(const f16x8*)tptrc((const f16*)hs[cur_], l16, q*64 + lhi*16);  \
    }                                                                          \
    f32x4 aR = bR, aZ = bZ, aXn = bXn, aHn = bHn;                              \
    _Pragma("unroll")                                                          \
    for (int q = 0; q < 4; ++q) {                                              \
      aR  = __builtin_amdgcn_mfma_f32_16x16x32_f16(wih[0][q], xb[q], aR, 0,0,0);  \
      aZ  = __builtin_amdgcn_mfma_f32_16x16x32_f16(wih[1][q], xb[q], aZ, 0,0,0);  \
      aXn = __builtin_amdgcn_mfma_f32_16x16x32_f16(wih[2][q], xb[q], aXn,0,0,0);  \
      aHn = __builtin_amdgcn_mfma_f32_16x16x32_f16(whh[2][q], hb[q], aHn,0,0,0);  \
    }                                                                          \
    _Pragma("unroll")                                                          \
    for (int q = 0; q < 4; ++q) {                                              \
      aR  = __builtin_amdgcn_mfma_f32_16x16x32_f16(whh[0][q], hb[q], aR, 0,0,0);  \
      aZ  = __builtin_amdgcn_mfma_f32_16x16x32_f16(whh[1][q], hb[q], aZ, 0,0,0);  \
    }                                                                          \
    float at_ = 0.f;                                                           \
    if (AUG) at_ = atts[cur_][l16];   /* broadcast read */                     \
    float hn_[4];                                                              \
    _Pragma("unroll")                                                          \
    for (int i = 0; i < 4; ++i) {                                              \
      float r = sigmoidf_(aR[i]);                                              \
      float z = sigmoidf_(aZ[i]);                                              \
      float n = tanhf_(aXn[i] + r * aHn[i]);                                   \
      float h;                                                                 \
      if (AUG) { float u = z * at_; h = hold[i] + u * (n - hold[i]); }         \
      else     { h = n + z * (hold[i] - n); }                                  \
      hold[i] = h; hn_[i] = h;                                                 \
    }                                                                          \
    f16x4 hv = {(f16)hn_[0], (f16)hn_[1], (f16)hn_[2], (f16)hn_[3]};           \
    *(f16x4*)tptr(hs[nxt_], l16, 2 * c4) = hv;                                 \
    if (!AUG) {                                                                \
      *(f16x4*)(histo + ((size_t)(b0 + l16) * T + t5_) * H + c4) = hv;         \
    } else {                                                                   \
      if (t5_ == len_l - 1) {                                                  \
        f32x4 ov = {hn_[0], hn_[1], hn_[2], hn_[3]};                           \
        *(f32x4*)(outp + (size_t)(b0 + l16) * H + c4) = ov;                    \
      }                                                                        \
    }                                                                          \
    /* write staged next-step input (loaded one full step ago) */              \
    if (t5_ + 1 < T) {                                                         \
      if (AUG) {                                                               \
        *(f16x4*)tptr(xs[nxt_], srow, cc * 8) = PW16;                          \
        if (tid < 16) atts[nxt_][tid] = AW;                                    \
      } else {                                                                 \
        f16x4 s4 = {(f16)PW32.x, (f16)PW32.y, (f16)PW32.z, (f16)PW32.w};       \
        *(f16x4*)tptr(xs[nxt_], srow, cc * 8) = s4;                            \
      }                                                                        \
    }                                                                          \
    __syncthreads();                                                           \
  }

  for (int t = 0; t < T; t += 2) {
    STEP(t,     Pa32, Pb32, Pa16, Pb16, Aa, Ab)
    STEP(t + 1, Pb32, Pa32, Pb16, Pa16, Ab, Aa)
  }
#undef STEP
}

// ---------------- DIN attention: per-b effective weight + masked softmax ----------------
// (unchanged from R1 — correct, small share of runtime)
__global__ __launch_bounds__(256)
void attn_kernel(const float* __restrict__ query,
                 const f16*   __restrict__ hist,
                 const int*   __restrict__ mask,
                 const float* __restrict__ W1,   // [36][4H]
                 const float* __restrict__ b1,
                 const float* __restrict__ W2,   // [1][36]
                 const float* __restrict__ b2,
                 float*       __restrict__ attv, // [B,T]
                 int T)
{
  __shared__ float qs[H];
  __shared__ float Wq[AH][H];
  __shared__ float qc[AH];
  __shared__ float red[256];

  const int tid = threadIdx.x;
  const int b   = blockIdx.x;

  if (tid < H) qs[tid] = query[b * H + tid];
  __syncthreads();

  for (int i = tid; i < AH * H; i += 256) {
    int u = i >> 7, k = i & (H - 1);
    const float* r = W1 + u * 4 * H;
    Wq[u][k] = r[H + k] - r[2 * H + k] + qs[k] * r[3 * H + k];
  }
  if (tid < AH) {
    const float* r = W1 + tid * 4 * H;
    float s = b1[tid];
    for (int k = 0; k < H; ++k) s += qs[k] * (r[k] + r[2 * H + k]);
    qc[tid] = s;
  }
  __syncthreads();

  float logit = -1e30f;
  int   mk = 0;
  const int t = tid;
  if (t < T) {
    mk = mask[(size_t)b * T + t];
    float acc[AH];
    #pragma unroll
    for (int u = 0; u < AH; ++u) acc[u] = qc[u];
    const f16* hr = hist + ((size_t)b * T + t) * H;
    for (int kc = 0; kc < H / 8; ++kc) {
      f16x8 hv = *(const f16x8*)(hr + kc * 8);
      float hf[8];
      #pragma unroll
      for (int j = 0; j < 8; ++j) hf[j] = (float)hv[j];
      #pragma unroll
      for (int u = 0; u < AH; ++u) {
        f32x4 w0 = *(const f32x4*)&Wq[u][kc * 8];
        f32x4 w1 = *(const f32x4*)&Wq[u][kc * 8 + 4];
        acc[u] += hf[0]*w0.x + hf[1]*w0.y + hf[2]*w0.z + hf[3]*w0.w
                + hf[4]*w1.x + hf[5]*w1.y + hf[6]*w1.z + hf[7]*w1.w;
      }
    }
    float lg = b2[0];
    #pragma unroll
    for (int u = 0; u < AH; ++u) lg += sigmoidf_(acc[u]) * W2[u];
    logit = (mk > 0) ? lg : -1e30f;
  }

  red[tid] = logit; __syncthreads();
  for (int s = 128; s > 0; s >>= 1) { if (tid < s) red[tid] = fmaxf(red[tid], red[tid + s]); __syncthreads(); }
  float mx = red[0]; __syncthreads();
  float ev = (t < T && mk > 0) ? __expf(logit - mx) : 0.f;
  red[tid] = ev; __syncthreads();
  for (int s = 128; s > 0; s >>= 1) { if (tid < s) red[tid] += red[tid + s]; __syncthreads(); }
  float sm = red[0];
  if (t < T) attv[(size_t)b * T + t] = ev / sm;
}

// ---------------- host ----------------
extern "C" void kernel_launch(void* const* d_in, const int* in_sizes, int n_in,
                              void* d_out, int out_size, void* d_ws, size_t ws_size,
                              hipStream_t stream)
{
  const float* query = (const float*)d_in[0];
  const float* ub    = (const float*)d_in[1];
  const int*   mask  = (const int*)d_in[2];
  const float* gWih  = (const float*)d_in[3];
  const float* gWhh  = (const float*)d_in[4];
  const float* gbih  = (const float*)d_in[5];
  const float* gbhh  = (const float*)d_in[6];
  const float* aW1   = (const float*)d_in[7];
  const float* ab1   = (const float*)d_in[8];
  const float* aW2   = (const float*)d_in[9];
  const float* ab2   = (const float*)d_in[10];
  const float* uWih  = (const float*)d_in[11];
  const float* uWhh  = (const float*)d_in[12];
  const float* ubih  = (const float*)d_in[13];
  const float* ubhh  = (const float*)d_in[14];

  const int B = in_sizes[0] / H;            // 1024
  const int T = in_sizes[1] / in_sizes[0];  // 200

  // workspace layout
  char*  ws   = (char*)d_ws;
  f16*   wf   = (f16*)ws;                                   // 4 * 384*128 f16 = 393216 B
  int*   len  = (int*)(ws + 393216);                        // B * 4
  float* attb = (float*)(ws + 393216 + 4096);               // B*T*4
  f16*   hist = (f16*)(ws + 393216 + 4096 + (size_t)B * T * 4); // B*T*H f16

  prep_weights<<<(4 * G3 * H + 255) / 256, 256, 0, stream>>>(gWih, gWhh, uWih, uWhh, wf);
  prep_len<<<(B + 255) / 256, 256, 0, stream>>>(mask, len, T, B);

  scan_kernel<false><<<B / 16, 512, 0, stream>>>(
      ub, (const f16*)nullptr, wf, wf + G3 * H, gbih, gbhh,
      (const float*)nullptr, (const int*)nullptr, hist, (float*)nullptr, T);

  attn_kernel<<<B, 256, 0, stream>>>(query, hist, mask, aW1, ab1, aW2, ab2, attb, T);

  scan_kernel<true><<<B / 16, 512, 0, stream>>>(
      (const float*)nullptr, hist, wf + 2 * G3 * H, wf + 3 * G3 * H, ubih, ubhh,
      attb, len, (f16*)nullptr, (float*)d_out, T);
}